// Round 16
// baseline (53.014 us; speedup 1.0000x reference)
//
#include <hip/hip_runtime.h>
#include <math.h>
#include <stdint.h>

#define NCLS 128
#define NBANK 8
constexpr float ALPHA = 0.5f;
constexpr float BETA_ = 0.5f;
constexpr float EPS_ = 1e-9f;

// ws: gLb[128][8] double (8192 B) | gceb[8] double (64 B) | gcntb[128][8] uint (4096 B)
__global__ void zero_ws(uint32_t* __restrict__ ws) {
    const int t = threadIdx.x;               // 256 threads, 3088 words
    for (int i = t; i < 3088; i += 256) ws[i] = 0u;
}

// R15 winner (banked atomics) + explicit A/B software pipeline with slim live
// state: v[8] is consumed inside EXP (S/vsel/e0 extracted, ~24 regs carried),
// so LOAD(next) sits in flight under REDUCE(cur)+EXP(next) (~800 cyc) and the
// wave never drains to zero bytes outstanding (the intra-wave convoy of R1-R15).
// 512 blocks x 512 threads = same 4096-wave mapping as R15.
__global__ __launch_bounds__(512, 2) void loss_main(
    const float* __restrict__ y_pred,
    const int*   __restrict__ y_true,
    double* __restrict__ gLb, unsigned int* __restrict__ gcntb,
    double* __restrict__ gceb, int nrows)
{
    __shared__ float    sL[NCLS];
    __shared__ unsigned scnt[NCLS];
    __shared__ float    sce;

    const int t = threadIdx.x;
    if (t == 0) sce = 0.f;
    if (t < NCLS) { sL[t] = 0.f; scnt[t] = 0u; }
    __syncthreads();

    const int lane = t & 63;
    const int half = lane >> 5;
    const int l32  = lane & 31;
    const int wgl  = blockIdx.x * (blockDim.x >> 6) + (t >> 6);   // 0..4095
    const int nW   = gridDim.x * (blockDim.x >> 6);               // 4096
    const int nPairs = nrows >> 1;
    const int step = nW * 8;

    float ce_local = 0.f;

    auto LOAD = [&](float4 (&V)[8], int (&L)[8], int pb) {
        const float* base = y_pred + ((size_t)(pb << 1) + half) * NCLS + (l32 << 2);
        #pragma unroll
        for (int u = 0; u < 8; ++u) {
            V[u] = *reinterpret_cast<const float4*>(base + (size_t)(u << 1) * NCLS);
            L[u] = y_true[((pb + u) << 1) + half];
        }
    };
    // consumes V entirely: after EXP only S/vs/e0 (+labels) stay live
    auto EXP = [&](const float4 (&V)[8], const int (&L)[8],
                   float (&S)[8], float (&vs)[8], float (&e0)[8]) {
        #pragma unroll
        for (int u = 0; u < 8; ++u) {
            const float ex = __expf(V[u].x), ey = __expf(V[u].y);
            const float ez = __expf(V[u].z), ew = __expf(V[u].w);
            e0[u] = ex;
            S[u]  = (ex + ey) + (ez + ew);
            const int ls = L[u] & 3;
            vs[u] = (ls == 0) ? V[u].x : (ls == 1) ? V[u].y
                  : (ls == 2) ? V[u].z : V[u].w;
        }
    };
    auto REDU = [&](float (&S)[8], const float (&vs)[8], const float (&e0)[8],
                    const int (&L)[8]) {
        #pragma unroll
        for (int off = 16; off; off >>= 1) {
            #pragma unroll
            for (int u = 0; u < 8; ++u) S[u] += __shfl_xor(S[u], off);
        }
        float tv[8];
        #pragma unroll
        for (int u = 0; u < 8; ++u)
            tv[u] = __shfl(vs[u], (half << 5) + (L[u] >> 2));
        if (l32 == 0) {
            #pragma unroll
            for (int u = 0; u < 8; ++u) {
                ce_local += tv[u] - __logf(S[u]);
                const float p1 = e0[u] / S[u];
                const float contrib = (L[u] == 0) ? ALPHA * __logf(p1 + EPS_)
                                                  : __logf(1.f - p1 + EPS_);
                atomicAdd(&sL[L[u]], contrib);
                atomicAdd(&scnt[L[u]], 1u);
            }
        }
    };

    int p = wgl * 8;
    if (p + 7 < nPairs) {
        float4 VA[8], VB[8]; int LA[8], LB[8];
        float SA[8], vsA[8], e0A[8], SB[8], vsB[8], e0B[8];
        LOAD(VA, LA, p);
        int pn = p + step;
        bool hn = (pn + 7 < nPairs);
        if (hn) LOAD(VB, LB, pn);                 // B in flight before A compute
        while (true) {
            EXP(VA, LA, SA, vsA, e0A);            // VA dead after this
            {
                const int p2 = pn + step;         // issue A-next under REDU(A)+EXP(B)
                if (hn && p2 + 7 < nPairs) LOAD(VA, LA, p2);
            }
            REDU(SA, vsA, e0A, LA);
            p = pn;
            if (!hn) break;
            pn = p + step;
            hn = (pn + 7 < nPairs);
            // roles swapped: process B, A (if loaded) is in flight
            EXP(VB, LB, SB, vsB, e0B);
            {
                const int p2 = pn + step;
                if (hn && p2 + 7 < nPairs) LOAD(VB, LB, p2);
            }
            REDU(SB, vsB, e0B, LB);
            p = pn;
            if (!hn) break;
            pn = p + step;
            hn = (pn + 7 < nPairs);
        }
    }
    // generic tail: leftover single pairs for this wave
    for (; p < nPairs; p += 1) {
        if (p < wgl * 8 || ((p - wgl * 8) % step) >= 8) break; // only own chunk
        const int row = (p << 1) + half;
        const float4 v = *reinterpret_cast<const float4*>(
            y_pred + (size_t)row * NCLS + (l32 << 2));
        const int lab = y_true[row];
        const float ex = __expf(v.x), ey = __expf(v.y);
        const float ez = __expf(v.z), ew = __expf(v.w);
        float S = (ex + ey) + (ez + ew);
        #pragma unroll
        for (int off = 16; off; off >>= 1) S += __shfl_xor(S, off);
        const int ls = lab & 3;
        const float vsel = (ls == 0) ? v.x : (ls == 1) ? v.y : (ls == 2) ? v.z : v.w;
        const float tv = __shfl(vsel, (half << 5) + (lab >> 2));
        if (l32 == 0) {
            ce_local += tv - __logf(S);
            const float p1 = ex / S;
            const float contrib = (lab == 0) ? ALPHA * __logf(p1 + EPS_)
                                             : __logf(1.f - p1 + EPS_);
            atomicAdd(&sL[lab], contrib);
            atomicAdd(&scnt[lab], 1u);
        }
    }
    if ((nrows & 1) && wgl == 0) {
        const int row = nrows - 1;
        const float4 v = *reinterpret_cast<const float4*>(
            y_pred + (size_t)row * NCLS + (l32 << 2));
        const int lab = y_true[row];
        if (half == 0) {
            const float ex = __expf(v.x), ey = __expf(v.y);
            const float ez = __expf(v.z), ew = __expf(v.w);
            float S = (ex + ey) + (ez + ew);
            #pragma unroll
            for (int off = 16; off; off >>= 1) S += __shfl_xor(S, off);
            const int ls = lab & 3;
            const float vsel = (ls == 0) ? v.x : (ls == 1) ? v.y : (ls == 2) ? v.z : v.w;
            const float tv = __shfl(vsel, (half << 5) + (lab >> 2));
            if (l32 == 0) {
                ce_local += tv - __logf(S);
                const float p1 = ex / S;
                const float contrib = (lab == 0) ? ALPHA * __logf(p1 + EPS_)
                                                 : __logf(1.f - p1 + EPS_);
                atomicAdd(&sL[lab], contrib);
                atomicAdd(&scnt[lab], 1u);
            }
        }
    }

    float lp = ce_local;
    #pragma unroll
    for (int off = 32; off; off >>= 1) lp += __shfl_xor(lp, off);
    if (lane == 0) atomicAdd(&sce, lp);
    __syncthreads();

    // banked flush: 512 blocks / 8 banks -> 64-deep chains on 1024 addresses
    const int bank = blockIdx.x & (NBANK - 1);
    if (t < NCLS) {
        const int c = (t + blockIdx.x) & (NCLS - 1);
        if (scnt[c]) {
            atomicAdd(&gLb[c * NBANK + bank], (double)sL[c]);
            atomicAdd(&gcntb[c * NBANK + bank], scnt[c]);
        }
    }
    if (t == 0) atomicAdd(&gceb[bank], (double)sce);
}

__global__ void loss_final(const double* __restrict__ gLb,
                           const unsigned int* __restrict__ gcntb,
                           const double* __restrict__ gceb,
                           float* __restrict__ out, int nrows)
{
    const int lane = threadIdx.x;   // 64 threads
    double cnt0 = 0.0;
    #pragma unroll
    for (int b = 0; b < NBANK; ++b) cnt0 += (double)gcntb[0 * NBANK + b];
    const double denom = (double)nrows - cnt0;

    double local = 0.0;
    for (int c = lane; c < NCLS; c += 64) {
        double Lc = 0.0, nc = 0.0;
        #pragma unroll
        for (int b = 0; b < NBANK; ++b) {
            Lc += gLb[c * NBANK + b];
            nc += (double)gcntb[c * NBANK + b];
        }
        if (c == 0) local += Lc;                          // ALPHA pre-applied
        else        local += (double)BETA_ * (1.0 - nc / denom) * Lc;
    }
    #pragma unroll
    for (int off = 32; off; off >>= 1) local += __shfl_down(local, off);
    if (lane == 0) {
        double ce = 0.0;
        #pragma unroll
        for (int b = 0; b < NBANK; ++b) ce += gceb[b];
        ce = -ce / (double)nrows;
        out[0] = (float)(ce - local / (double)nrows);
    }
}

extern "C" void kernel_launch(void* const* d_in, const int* in_sizes, int n_in,
                              void* d_out, int out_size, void* d_ws, size_t ws_size,
                              hipStream_t stream) {
    const float* y_pred = (const float*)d_in[0];
    const int*   y_true = (const int*)d_in[1];
    const int nrows = in_sizes[1];

    double*   gLb   = (double*)d_ws;                       // 8192 B
    double*   gceb  = (double*)((char*)d_ws + 8192);       // 64 B
    unsigned* gcntb = (unsigned*)((char*)d_ws + 8256);     // 4096 B

    zero_ws<<<dim3(1), dim3(256), 0, stream>>>((uint32_t*)d_ws);

    loss_main<<<dim3(512), dim3(512), 0, stream>>>(y_pred, y_true, gLb, gcntb, gceb, nrows);
    loss_final<<<dim3(1), dim3(64), 0, stream>>>(gLb, gcntb, gceb, (float*)d_out, nrows);
}